// Round 5
// baseline (82.992 us; speedup 1.0000x reference)
//
#include <hip/hip_runtime.h>

#define N_ROWS 8192
#define BM 128
#define CHUNK 256
#define BN 64
#define NITER (CHUNK / BN)       // 4
#define NCHUNK (N_ROWS / CHUNK)  // 32
#define NPART NCHUNK             // wc halves combined in-block
#define KEXP 20.60992915f        // log2(e)/TAU

typedef __attribute__((ext_vector_type(8))) short short8;
typedef __attribute__((ext_vector_type(4))) float f32x4;

__device__ __forceinline__ void gload_lds16(const void* g, void* l) {
  __builtin_amdgcn_global_load_lds(
      (const __attribute__((address_space(1))) void*)g,
      (__attribute__((address_space(3))) void*)l, 16, 0, 0);
}

__device__ __forceinline__ unsigned short f2bf(float x) {
  unsigned int u = __float_as_uint(x);
  unsigned int r = (u + 0x7fffu + ((u >> 16) & 1u)) >> 16;
  return (unsigned short)r;
}

__device__ __forceinline__ float fast_exp2(float x) {
  float r;
  asm("v_exp_f32 %0, %1" : "=v"(r) : "v"(x));
  return r;
}

// Kernel 1: L2-normalize rows; write TWO bf16 arrays, both 16B-chunk-swizzled
// (chunk ^= row&7): fnA scaled by log2(e)/tau (MFMA A operand), fnB unscaled.
__global__ __launch_bounds__(256) void knorm(const float* __restrict__ feat,
                                             unsigned int* __restrict__ fnA,
                                             unsigned int* __restrict__ fnB) {
  const int wid = threadIdx.x >> 6;
  const int lane = threadIdx.x & 63;
  const int row = blockIdx.x * 4 + wid;
  const float2 v = *(const float2*)(feat + (size_t)row * 128 + lane * 2);
  float s = v.x * v.x + v.y * v.y;
#pragma unroll
  for (int m = 1; m < 64; m <<= 1) s += __shfl_xor(s, m);
  const float inv = 1.0f / fmaxf(sqrtf(s), 1e-12f);
  const float x = v.x * inv, y = v.y * inv;
  const int idx = row * 64 + ((lane >> 2) ^ (row & 7)) * 4 + (lane & 3);
  fnB[idx] = (unsigned int)f2bf(x) | ((unsigned int)f2bf(y) << 16);
  fnA[idx] = (unsigned int)f2bf(x * KEXP) | ((unsigned int)f2bf(y * KEXP) << 16);
}

// Kernel 2: block = 128 rows x 256 cols; 4 waves 2x2 (wave tile 64x32).
// A frags global->regs once; B panel (64KB) staged ONCE into LDS, ONE barrier;
// inner 4 subtile iters are barrier-free (read-only LDS).
__global__ __launch_bounds__(256, 2) void ksim(const unsigned int* __restrict__ fnA,
                                               const unsigned int* __restrict__ fnB,
                                               const float* __restrict__ alphap,
                                               float* __restrict__ posP,
                                               float* __restrict__ totP) {
  __shared__ __align__(16) char smem[65536];  // B panel: 256 rows x 256B
  const int tid = threadIdx.x;
  const int lane = tid & 63;
  const int wid = tid >> 6;
  const int wr = wid >> 1, wc = wid & 1;
  const int r0 = blockIdx.x * BM;
  const int c0 = blockIdx.y * CHUNK;
  const float alphaK = alphap[0] * KEXP;

  const char* __restrict__ FA = (const char*)fnA;
  const char* __restrict__ FB = (const char*)fnB;

  // Stage B panel: per wave 16 x gload_lds16, rows wid*64 + s*4 + (lane>>4).
  {
    const char* g = FB + (size_t)(c0 + wid * 64 + (lane >> 4)) * 256 + (lane & 15) * 16;
    char* l = smem + wid * 16384;
#pragma unroll
    for (int s = 0; s < 16; s++) gload_lds16(g + s * 1024, l + s * 1024);
  }

  // A fragments: 4 m-frags x 4 k-steps, swizzled read from global (L2-resident).
  short8 aR[4][4];
#pragma unroll
  for (int m = 0; m < 4; m++) {
    const int r = r0 + wr * 64 + m * 16 + (lane & 15);
#pragma unroll
    for (int ks = 0; ks < 4; ks++) {
      const int ch = (ks * 4 + (lane >> 4)) ^ (r & 7);
      aR[m][ks] = *(const short8*)(FA + (size_t)r * 256 + ch * 16);
    }
  }
  __syncthreads();  // single barrier: B panel ready

  float pp[4][4] = {{0.f}}, tp[4][4] = {{0.f}};

#pragma unroll
  for (int it = 0; it < NITER; ++it) {
    f32x4 acc[4][2];
#pragma unroll
    for (int m = 0; m < 4; m++)
#pragma unroll
      for (int n = 0; n < 2; n++) acc[m][n] = (f32x4){0.f, 0.f, 0.f, 0.f};

    const int rB0 = it * BN + wc * 32 + (lane & 15);
#pragma unroll
    for (int ks = 0; ks < 4; ks++) {
      const int ch = (ks * 4 + (lane >> 4)) ^ (lane & 7);
      const short8 b0 = *(const short8*)(smem + rB0 * 256 + ch * 16);
      const short8 b1 = *(const short8*)(smem + (rB0 + 16) * 256 + ch * 16);
#pragma unroll
      for (int m = 0; m < 4; m++) {
        acc[m][0] = __builtin_amdgcn_mfma_f32_16x16x32_bf16(aR[m][ks], b0, acc[m][0], 0, 0, 0);
        acc[m][1] = __builtin_amdgcn_mfma_f32_16x16x32_bf16(aR[m][ks], b1, acc[m][1], 0, 0, 0);
      }
    }

    // Epilogue: a = sim*log2e/tau (pre-scaled). e = 2^a; tot += e; pos += e if a>=alphaK.
    const int cb = c0 + it * BN;
#pragma unroll
    for (int m = 0; m < 4; m++) {
      const int grb = r0 + wr * 64 + m * 16;
#pragma unroll
      for (int n = 0; n < 2; n++) {
        const int gcb = cb + wc * 32 + n * 16;
        const f32x4 a = acc[m][n];
        if (grb == gcb) {  // diagonal fragment: self-exclusion
          const int gr0 = (lane >> 4) << 2;
          const int gcl = lane & 15;
#pragma unroll
          for (int r = 0; r < 4; r++) {
            const float e = fast_exp2(a[r]);
            const float ev = (gr0 + r == gcl) ? 0.0f : e;
            tp[m][r] += ev;
            pp[m][r] += (a[r] >= alphaK) ? ev : 0.0f;
          }
        } else {
#pragma unroll
          for (int r = 0; r < 4; r++) {
            const float e = fast_exp2(a[r]);
            tp[m][r] += e;
            pp[m][r] += (a[r] >= alphaK) ? e : 0.0f;
          }
        }
      }
    }
  }

  // 16-col-lane shfl reduce.
#pragma unroll
  for (int m = 0; m < 4; m++)
#pragma unroll
    for (int r = 0; r < 4; r++) {
      float p = pp[m][r], t = tp[m][r];
#pragma unroll
      for (int msk = 1; msk < 16; msk <<= 1) {
        p += __shfl_xor(p, msk);
        t += __shfl_xor(t, msk);
      }
      pp[m][r] = p;
      tp[m][r] = t;
    }

  // Combine wc halves via (now dead) LDS, then one coalesced-ish store per row.
  __syncthreads();  // all B reads done; smem reusable
  float* red = (float*)smem;  // [2 wr][64 rows][2]
  if (wc == 1 && (lane & 15) == 0) {
    const int g = lane >> 4;
#pragma unroll
    for (int m = 0; m < 4; m++)
#pragma unroll
      for (int r = 0; r < 4; r++) {
        const int rl = m * 16 + g * 4 + r;
        red[(wr * 64 + rl) * 2 + 0] = pp[m][r];
        red[(wr * 64 + rl) * 2 + 1] = tp[m][r];
      }
  }
  __syncthreads();
  if (wc == 0 && (lane & 15) == 0) {
    const int g = lane >> 4;
#pragma unroll
    for (int m = 0; m < 4; m++)
#pragma unroll
      for (int r = 0; r < 4; r++) {
        const int rl = m * 16 + g * 4 + r;
        const int row = r0 + wr * 64 + rl;
        posP[blockIdx.y * N_ROWS + row] = pp[m][r] + red[(wr * 64 + rl) * 2 + 0];
        totP[blockIdx.y * N_ROWS + row] = tp[m][r] + red[(wr * 64 + rl) * 2 + 1];
      }
  }
}

// Kernel 3a: per-row loss term, 128-row blocks -> 64 partial sums.
__global__ __launch_bounds__(128) void kred1(const float* __restrict__ posP,
                                             const float* __restrict__ totP,
                                             float* __restrict__ bp) {
  const int t = threadIdx.x;
  const int row = blockIdx.x * 128 + t;
  float pos = 0.f, tot = 0.f;
#pragma unroll
  for (int c = 0; c < NPART; c++) {
    pos += posP[c * N_ROWS + row];
    tot += totP[c * N_ROWS + row];
  }
  float term = __logf(tot + 2e-10f) - __logf(pos + 1e-10f);
#pragma unroll
  for (int m = 1; m < 64; m <<= 1) term += __shfl_xor(term, m);
  __shared__ float s2[2];
  if ((t & 63) == 0) s2[t >> 6] = term;
  __syncthreads();
  if (t == 0) bp[blockIdx.x] = s2[0] + s2[1];
}

// Kernel 3b: final mean.
__global__ void kred2(const float* __restrict__ bp, float* __restrict__ out) {
  const int l = threadIdx.x;
  float v = bp[l];
#pragma unroll
  for (int m = 1; m < 64; m <<= 1) v += __shfl_xor(v, m);
  if (l == 0) out[0] = v * (1.0f / 8192.0f);
}

extern "C" void kernel_launch(void* const* d_in, const int* in_sizes, int n_in,
                              void* d_out, int out_size, void* d_ws, size_t ws_size,
                              hipStream_t stream) {
  const float* feat = (const float*)d_in[0];
  const float* alphap = (const float*)d_in[1];
  char* ws = (char*)d_ws;
  unsigned int* fnA = (unsigned int*)ws;                    // 2 MB bf16 swizzled, x log2e/tau
  unsigned int* fnB = (unsigned int*)(ws + (2u << 20));     // 2 MB bf16 swizzled
  float* posP = (float*)(ws + (4u << 20));                  // 1 MB (32 x 8192)
  float* totP = (float*)(ws + (5u << 20));                  // 1 MB
  float* bp = (float*)(ws + (6u << 20));                    // 256 B
  float* out = (float*)d_out;

  knorm<<<dim3(N_ROWS / 4), dim3(256), 0, stream>>>(feat, fnA, fnB);
  ksim<<<dim3(N_ROWS / BM, NCHUNK), dim3(256), 0, stream>>>(fnA, fnB, alphap, posP, totP);
  kred1<<<dim3(N_ROWS / 128), dim3(128), 0, stream>>>(posP, totP, bp);
  kred2<<<dim3(1), dim3(64), 0, stream>>>(bp, out);
}

// Round 6
// 54.712 us; speedup vs baseline: 1.5169x; 1.5169x over previous
//
#include <hip/hip_runtime.h>

#define N_ROWS 8192
#define BM 128
#define CHUNK 128
#define NCHUNK (N_ROWS / CHUNK)  // 64
#define NPART NCHUNK             // 64 column-partials per row
#define KEXP 20.60992915f        // log2(e)/TAU

typedef __attribute__((ext_vector_type(8))) short short8;
typedef __attribute__((ext_vector_type(4))) float f32x4;

__device__ __forceinline__ void gload_lds16(const void* g, void* l) {
  __builtin_amdgcn_global_load_lds(
      (const __attribute__((address_space(1))) void*)g,
      (__attribute__((address_space(3))) void*)l, 16, 0, 0);
}

__device__ __forceinline__ unsigned short f2bf(float x) {
  unsigned int u = __float_as_uint(x);
  unsigned int r = (u + 0x7fffu + ((u >> 16) & 1u)) >> 16;
  return (unsigned short)r;
}

__device__ __forceinline__ float fast_exp2(float x) {
  float r;
  asm("v_exp_f32 %0, %1" : "=v"(r) : "v"(x));
  return r;
}

// Kernel 1: L2-normalize rows. fnA: PLAIN row-major, scaled by log2(e)/tau
// (A operand, read straight to regs). fnB: 16B-chunk-swizzled (chunk ^= row&7),
// unscaled (B operand, staged linearly into LDS then swizzle-read).
__global__ __launch_bounds__(256) void knorm(const float* __restrict__ feat,
                                             unsigned int* __restrict__ fnA,
                                             unsigned int* __restrict__ fnB) {
  const int wid = threadIdx.x >> 6;
  const int lane = threadIdx.x & 63;
  const int row = blockIdx.x * 4 + wid;
  const float2 v = *(const float2*)(feat + (size_t)row * 128 + lane * 2);
  float s = v.x * v.x + v.y * v.y;
#pragma unroll
  for (int m = 1; m < 64; m <<= 1) s += __shfl_xor(s, m);
  const float inv = 1.0f / fmaxf(sqrtf(s), 1e-12f);
  const float x = v.x * inv, y = v.y * inv;
  fnA[row * 64 + lane] = (unsigned int)f2bf(x * KEXP) |
                         ((unsigned int)f2bf(y * KEXP) << 16);
  const int idx = row * 64 + ((lane >> 2) ^ (row & 7)) * 4 + (lane & 3);
  fnB[idx] = (unsigned int)f2bf(x) | ((unsigned int)f2bf(y) << 16);
}

// Kernel 2: block = 128 rows x 128 cols. 4 waves, each = 32 rows x 128 cols.
// 32KB LDS B panel staged once; one barrier; 2 x 64-col compute halves.
// launch_bounds(256,4): 4 blocks/CU, VGPR<=128 (est ~115).
__global__ __launch_bounds__(256, 4) void ksim(const unsigned int* __restrict__ fnA,
                                               const unsigned int* __restrict__ fnB,
                                               const float* __restrict__ alphap,
                                               float* __restrict__ posP,
                                               float* __restrict__ totP) {
  __shared__ __align__(16) char smem[32768];  // B panel: 128 rows x 256B
  const int tid = threadIdx.x;
  const int lane = tid & 63;
  const int wid = tid >> 6;
  const int r0 = blockIdx.x * BM;
  const int c0 = blockIdx.y * CHUNK;
  const float alphaK = alphap[0] * KEXP;

  const char* __restrict__ FA = (const char*)fnA;
  const char* __restrict__ FB = (const char*)fnB;

  // Stage B panel: 8 x gload_lds16 per wave (wave wid stages rows wid*32..+32).
  {
    const char* g = FB + (size_t)(c0 + wid * 32 + (lane >> 4)) * 256 + (lane & 15) * 16;
    char* l = smem + wid * 8192;
#pragma unroll
    for (int s = 0; s < 8; s++) gload_lds16(g + s * 1024, l + s * 1024);
  }

  // A fragments: 2 m-frags x 4 k-steps, PLAIN row-major reads (line-friendly).
  short8 aR[2][4];
#pragma unroll
  for (int m = 0; m < 2; m++) {
    const char* ar = FA + (size_t)(r0 + wid * 32 + m * 16 + (lane & 15)) * 256 + (lane >> 4) * 16;
#pragma unroll
    for (int ks = 0; ks < 4; ks++) aR[m][ks] = *(const short8*)(ar + ks * 64);
  }
  __syncthreads();  // B panel ready (also drains A loads)

  float pp[2][4] = {{0.f}}, tp[2][4] = {{0.f}};

#pragma unroll 1
  for (int it = 0; it < 2; ++it) {
    f32x4 acc[2][4];
#pragma unroll
    for (int m = 0; m < 2; m++)
#pragma unroll
      for (int n = 0; n < 4; n++) acc[m][n] = (f32x4){0.f, 0.f, 0.f, 0.f};

    const int rB0 = it * 64 + (lane & 15);
#pragma unroll
    for (int ks = 0; ks < 4; ks++) {
      const int ch = (ks * 4 + (lane >> 4)) ^ (lane & 7);
      const short8 b0 = *(const short8*)(smem + (rB0 + 0) * 256 + ch * 16);
      const short8 b1 = *(const short8*)(smem + (rB0 + 16) * 256 + ch * 16);
      const short8 b2 = *(const short8*)(smem + (rB0 + 32) * 256 + ch * 16);
      const short8 b3 = *(const short8*)(smem + (rB0 + 48) * 256 + ch * 16);
#pragma unroll
      for (int m = 0; m < 2; m++) {
        acc[m][0] = __builtin_amdgcn_mfma_f32_16x16x32_bf16(aR[m][ks], b0, acc[m][0], 0, 0, 0);
        acc[m][1] = __builtin_amdgcn_mfma_f32_16x16x32_bf16(aR[m][ks], b1, acc[m][1], 0, 0, 0);
        acc[m][2] = __builtin_amdgcn_mfma_f32_16x16x32_bf16(aR[m][ks], b2, acc[m][2], 0, 0, 0);
        acc[m][3] = __builtin_amdgcn_mfma_f32_16x16x32_bf16(aR[m][ks], b3, acc[m][3], 0, 0, 0);
      }
    }

    // Epilogue: a = sim*log2e/tau. e = 2^a; tot += e; pos += e if a>=alphaK.
    const int cb = c0 + it * 64;
#pragma unroll
    for (int m = 0; m < 2; m++) {
      const int grb = r0 + wid * 32 + m * 16;
#pragma unroll
      for (int n = 0; n < 4; n++) {
        const int gcb = cb + n * 16;
        const f32x4 a = acc[m][n];
        if (grb == gcb) {  // diagonal fragment: self-exclusion
          const int gr0 = (lane >> 4) << 2;
          const int gcl = lane & 15;
#pragma unroll
          for (int r = 0; r < 4; r++) {
            const float e = fast_exp2(a[r]);
            const float ev = (gr0 + r == gcl) ? 0.0f : e;
            tp[m][r] += ev;
            pp[m][r] += (a[r] >= alphaK) ? ev : 0.0f;
          }
        } else {
#pragma unroll
          for (int r = 0; r < 4; r++) {
            const float e = fast_exp2(a[r]);
            tp[m][r] += e;
            pp[m][r] += (a[r] >= alphaK) ? e : 0.0f;
          }
        }
      }
    }
  }

  // 16-col-lane shfl reduce; direct per-(row, chunk) partial store.
#pragma unroll
  for (int m = 0; m < 2; m++)
#pragma unroll
    for (int r = 0; r < 4; r++) {
      float p = pp[m][r], t = tp[m][r];
#pragma unroll
      for (int msk = 1; msk < 16; msk <<= 1) {
        p += __shfl_xor(p, msk);
        t += __shfl_xor(t, msk);
      }
      if ((lane & 15) == 0) {
        const int row = r0 + wid * 32 + m * 16 + ((lane >> 4) << 2) + r;
        posP[blockIdx.y * N_ROWS + row] = p;
        totP[blockIdx.y * N_ROWS + row] = t;
      }
    }
}

// Kernel 3a: per-row loss term, 128-row blocks -> 64 partial sums.
__global__ __launch_bounds__(128) void kred1(const float* __restrict__ posP,
                                             const float* __restrict__ totP,
                                             float* __restrict__ bp) {
  const int t = threadIdx.x;
  const int row = blockIdx.x * 128 + t;
  float pos = 0.f, tot = 0.f;
#pragma unroll
  for (int c = 0; c < NPART; c++) {
    pos += posP[c * N_ROWS + row];
    tot += totP[c * N_ROWS + row];
  }
  float term = __logf(tot + 2e-10f) - __logf(pos + 1e-10f);
#pragma unroll
  for (int m = 1; m < 64; m <<= 1) term += __shfl_xor(term, m);
  __shared__ float s2[2];
  if ((t & 63) == 0) s2[t >> 6] = term;
  __syncthreads();
  if (t == 0) bp[blockIdx.x] = s2[0] + s2[1];
}

// Kernel 3b: final mean.
__global__ void kred2(const float* __restrict__ bp, float* __restrict__ out) {
  const int l = threadIdx.x;
  float v = bp[l];
#pragma unroll
  for (int m = 1; m < 64; m <<= 1) v += __shfl_xor(v, m);
  if (l == 0) out[0] = v * (1.0f / 8192.0f);
}

extern "C" void kernel_launch(void* const* d_in, const int* in_sizes, int n_in,
                              void* d_out, int out_size, void* d_ws, size_t ws_size,
                              hipStream_t stream) {
  const float* feat = (const float*)d_in[0];
  const float* alphap = (const float*)d_in[1];
  char* ws = (char*)d_ws;
  unsigned int* fnA = (unsigned int*)ws;                    // 2 MB plain bf16, x log2e/tau
  unsigned int* fnB = (unsigned int*)(ws + (2u << 20));     // 2 MB swizzled bf16
  float* posP = (float*)(ws + (4u << 20));                  // 2 MB (64 x 8192)
  float* totP = (float*)(ws + (6u << 20));                  // 2 MB
  float* bp = (float*)(ws + (8u << 20));                    // 256 B
  float* out = (float*)d_out;

  knorm<<<dim3(N_ROWS / 4), dim3(256), 0, stream>>>(feat, fnA, fnB);
  ksim<<<dim3(N_ROWS / BM, NCHUNK), dim3(256), 0, stream>>>(fnA, fnB, alphap, posP, totP);
  kred1<<<dim3(N_ROWS / 128), dim3(128), 0, stream>>>(posP, totP, bp);
  kred2<<<dim3(1), dim3(64), 0, stream>>>(bp, out);
}

// Round 7
// 37.418 us; speedup vs baseline: 2.2180x; 1.4622x over previous
//
#include <hip/hip_runtime.h>

#define N_ROWS 8192
#define BM 128                   // rows per block
#define SEG 512                  // cols per block
#define TILE 64                  // cols per LDS tile
#define NTILE (SEG / TILE)       // 8
#define NSEG (N_ROWS / SEG)      // 16
#define NPART NSEG
#define KEXP 20.60992915f        // log2(e)/TAU

typedef __attribute__((ext_vector_type(8))) short short8;
typedef __attribute__((ext_vector_type(4))) float f32x4;

__device__ __forceinline__ void gload_lds16(const void* g, void* l) {
  __builtin_amdgcn_global_load_lds(
      (const __attribute__((address_space(1))) void*)g,
      (__attribute__((address_space(3))) void*)l, 16, 0, 0);
}

__device__ __forceinline__ unsigned short f2bf(float x) {
  unsigned int u = __float_as_uint(x);
  unsigned int r = (u + 0x7fffu + ((u >> 16) & 1u)) >> 16;
  return (unsigned short)r;
}

__device__ __forceinline__ float fast_exp2(float x) {
  float r;
  asm("v_exp_f32 %0, %1" : "=v"(r) : "v"(x));
  return r;
}

// Kernel 1: L2-normalize rows; write fn in MFMA-FRAGMENT order:
// fragment (row-group G = row>>4, k-step ks) = contiguous 1KB at
// G*4096 + ks*1024 + mfma_lane*16, mfma_lane = (ksub<<4)|(row&15).
// fnA scaled by log2(e)/tau, fnB unscaled.
__global__ __launch_bounds__(256) void knorm(const float* __restrict__ feat,
                                             unsigned int* __restrict__ fnA,
                                             unsigned int* __restrict__ fnB) {
  const int wid = threadIdx.x >> 6;
  const int lane = threadIdx.x & 63;
  const int row = blockIdx.x * 4 + wid;
  const float2 v = *(const float2*)(feat + (size_t)row * 128 + lane * 2);
  float s = v.x * v.x + v.y * v.y;
#pragma unroll
  for (int m = 1; m < 64; m <<= 1) s += __shfl_xor(s, m);
  const float inv = 1.0f / fmaxf(sqrtf(s), 1e-12f);
  const float x = v.x * inv, y = v.y * inv;
  // this lane holds row-chunk cc = lane>>2 (16B chunks), u32 sub-slot lane&3
  const int cc = lane >> 2;
  const int idx = ((row >> 4) << 10) + ((cc >> 2) << 8) + ((cc & 3) << 6) +
                  ((row & 15) << 2) + (lane & 3);
  fnB[idx] = (unsigned int)f2bf(x) | ((unsigned int)f2bf(y) << 16);
  fnA[idx] = (unsigned int)f2bf(x * KEXP) | ((unsigned int)f2bf(y * KEXP) << 16);
}

// Kernel 2: block = 128 rows x 512 cols (8 tiles of 64). 4 waves, wave = 32
// rows x 64 cols. A frags: coalesced 1KB loads once per block. B: fragment-
// ordered linear gload_lds dbuf (2x16KB), stage-early + one barrier per tile.
// All LDS reads stride-16B sequential -> zero bank conflicts.
__global__ __launch_bounds__(256, 4) void ksim(const unsigned int* __restrict__ fnA,
                                               const unsigned int* __restrict__ fnB,
                                               const float* __restrict__ alphap,
                                               float* __restrict__ posP,
                                               float* __restrict__ totP) {
  __shared__ __align__(16) char smem[32768];  // 2 x 16KB B tiles
  const int tid = threadIdx.x;
  const int lane = tid & 63;
  const int wid = tid >> 6;
  const int r0 = blockIdx.x * BM;
  const int c0 = blockIdx.y * SEG;
  const float alphaK = alphap[0] * KEXP;

  const char* __restrict__ FA = (const char*)fnA;
  const char* __restrict__ FB = (const char*)fnB;

  // A fragments: 2 m-frags x 4 ks, each a contiguous 1KB coalesced load.
  short8 aR[2][4];
  {
    const int G0 = (r0 + wid * 32) >> 4;
#pragma unroll
    for (int m = 0; m < 2; m++)
#pragma unroll
      for (int ks = 0; ks < 4; ks++)
        aR[m][ks] = *(const short8*)(FA + (size_t)(G0 + m) * 4096 + ks * 1024 + lane * 16);
  }

  // Stage tile 0: 16KB linear copy, 4 gload_lds per wave.
  {
    const char* g = FB + (size_t)(c0 >> 4) * 4096 + wid * 4096 + lane * 16;
    char* l = smem + wid * 4096;
#pragma unroll
    for (int s = 0; s < 4; s++) gload_lds16(g + s * 1024, l + s * 1024);
  }
  __syncthreads();

  float pp[2][4] = {{0.f}}, tp[2][4] = {{0.f}};
  int cur = 0;

#pragma unroll 1
  for (int it = 0; it < NTILE; ++it) {
    if (it + 1 < NTILE) {  // stage next tile into other buffer (early issue)
      const char* g = FB + (size_t)((c0 >> 4) + (it + 1) * 4) * 4096 + wid * 4096 + lane * 16;
      char* l = smem + (cur ^ 1) * 16384 + wid * 4096;
#pragma unroll
      for (int s = 0; s < 4; s++) gload_lds16(g + s * 1024, l + s * 1024);
    }

    f32x4 acc[2][4];
#pragma unroll
    for (int m = 0; m < 2; m++)
#pragma unroll
      for (int n = 0; n < 4; n++) acc[m][n] = (f32x4){0.f, 0.f, 0.f, 0.f};

    const char* Bb = smem + cur * 16384;
#pragma unroll
    for (int ks = 0; ks < 4; ks++) {
      const short8 b0 = *(const short8*)(Bb + 0 * 4096 + ks * 1024 + lane * 16);
      const short8 b1 = *(const short8*)(Bb + 1 * 4096 + ks * 1024 + lane * 16);
      const short8 b2 = *(const short8*)(Bb + 2 * 4096 + ks * 1024 + lane * 16);
      const short8 b3 = *(const short8*)(Bb + 3 * 4096 + ks * 1024 + lane * 16);
#pragma unroll
      for (int m = 0; m < 2; m++) {
        acc[m][0] = __builtin_amdgcn_mfma_f32_16x16x32_bf16(aR[m][ks], b0, acc[m][0], 0, 0, 0);
        acc[m][1] = __builtin_amdgcn_mfma_f32_16x16x32_bf16(aR[m][ks], b1, acc[m][1], 0, 0, 0);
        acc[m][2] = __builtin_amdgcn_mfma_f32_16x16x32_bf16(aR[m][ks], b2, acc[m][2], 0, 0, 0);
        acc[m][3] = __builtin_amdgcn_mfma_f32_16x16x32_bf16(aR[m][ks], b3, acc[m][3], 0, 0, 0);
      }
    }

    // Epilogue: a = sim*log2e/tau (A pre-scaled). e = 2^a; tot += e; pos += e if a>=alphaK.
    const int cb = c0 + it * TILE;
#pragma unroll
    for (int m = 0; m < 2; m++) {
      const int grb = r0 + wid * 32 + m * 16;
#pragma unroll
      for (int n = 0; n < 4; n++) {
        const int gcb = cb + n * 16;
        const f32x4 a = acc[m][n];
        if (grb == gcb) {  // diagonal fragment: self-exclusion
          const int gr0 = (lane >> 4) << 2;
          const int gcl = lane & 15;
#pragma unroll
          for (int r = 0; r < 4; r++) {
            const float e = fast_exp2(a[r]);
            const float ev = (gr0 + r == gcl) ? 0.0f : e;
            tp[m][r] += ev;
            pp[m][r] += (a[r] >= alphaK) ? ev : 0.0f;
          }
        } else {
#pragma unroll
          for (int r = 0; r < 4; r++) {
            const float e = fast_exp2(a[r]);
            tp[m][r] += e;
            pp[m][r] += (a[r] >= alphaK) ? e : 0.0f;
          }
        }
      }
    }
    __syncthreads();
    cur ^= 1;
  }

  // 16-col-lane shfl reduce; direct per-(row, segment) partial store.
#pragma unroll
  for (int m = 0; m < 2; m++)
#pragma unroll
    for (int r = 0; r < 4; r++) {
      float p = pp[m][r], t = tp[m][r];
#pragma unroll
      for (int msk = 1; msk < 16; msk <<= 1) {
        p += __shfl_xor(p, msk);
        t += __shfl_xor(t, msk);
      }
      if ((lane & 15) == 0) {
        const int row = r0 + wid * 32 + m * 16 + ((lane >> 4) << 2) + r;
        posP[blockIdx.y * N_ROWS + row] = p;
        totP[blockIdx.y * N_ROWS + row] = t;
      }
    }
}

// Kernel 3a: per-row loss term, 128-row blocks -> 64 partial sums.
__global__ __launch_bounds__(128) void kred1(const float* __restrict__ posP,
                                             const float* __restrict__ totP,
                                             float* __restrict__ bp) {
  const int t = threadIdx.x;
  const int row = blockIdx.x * 128 + t;
  float pos = 0.f, tot = 0.f;
#pragma unroll
  for (int c = 0; c < NPART; c++) {
    pos += posP[c * N_ROWS + row];
    tot += totP[c * N_ROWS + row];
  }
  float term = __logf(tot + 2e-10f) - __logf(pos + 1e-10f);
#pragma unroll
  for (int m = 1; m < 64; m <<= 1) term += __shfl_xor(term, m);
  __shared__ float s2[2];
  if ((t & 63) == 0) s2[t >> 6] = term;
  __syncthreads();
  if (t == 0) bp[blockIdx.x] = s2[0] + s2[1];
}

// Kernel 3b: final mean.
__global__ void kred2(const float* __restrict__ bp, float* __restrict__ out) {
  const int l = threadIdx.x;
  float v = bp[l];
#pragma unroll
  for (int m = 1; m < 64; m <<= 1) v += __shfl_xor(v, m);
  if (l == 0) out[0] = v * (1.0f / 8192.0f);
}

extern "C" void kernel_launch(void* const* d_in, const int* in_sizes, int n_in,
                              void* d_out, int out_size, void* d_ws, size_t ws_size,
                              hipStream_t stream) {
  const float* feat = (const float*)d_in[0];
  const float* alphap = (const float*)d_in[1];
  char* ws = (char*)d_ws;
  unsigned int* fnA = (unsigned int*)ws;                    // 2 MB frag-ordered bf16, x log2e/tau
  unsigned int* fnB = (unsigned int*)(ws + (2u << 20));     // 2 MB frag-ordered bf16
  float* posP = (float*)(ws + (4u << 20));                  // 512 KB (16 x 8192)
  float* totP = (float*)(ws + (5u << 20));                  // 512 KB
  float* bp = (float*)(ws + (6u << 20));                    // 256 B
  float* out = (float*)d_out;

  knorm<<<dim3(N_ROWS / 4), dim3(256), 0, stream>>>(feat, fnA, fnB);
  ksim<<<dim3(N_ROWS / BM, NSEG), dim3(256), 0, stream>>>(fnA, fnB, alphap, posP, totP);
  kred1<<<dim3(N_ROWS / 128), dim3(128), 0, stream>>>(posP, totP, bp);
  kred2<<<dim3(1), dim3(64), 0, stream>>>(bp, out);
}